// Round 7
// baseline (292.672 us; speedup 1.0000x reference)
//
#include <hip/hip_runtime.h>
#include <type_traits>

#define N_TOK 65536
#define K_CODE 8192
#define D_DIM 64

constexpr float DECAY = 0.9f;
constexpr float OMD = 0.1f;   // 1 - DECAY
constexpr float EPS = 1e-5f;

// ---- output layout (floats), per reference return order ----
constexpr int OUT_QE = 0;
constexpr int OUT_W  = 1;
constexpr int OUT_CS = 1 + K_CODE * D_DIM;
constexpr int OUT_EA = OUT_CS + K_CODE;

// ---- workspace layout (floats) ----
constexpr int WS_QE     = 0;
constexpr int WS_NSUM   = 16;                           // 8 slots, stride 32 floats (128B apart)
constexpr int WS_COUNTS = 16 + 8 * 32;                  // 272 (header ends here)
constexpr int WS_EMBSUM = WS_COUNTS + K_CODE;
constexpr int WS_WHI    = WS_EMBSUM + K_CODE * D_DIM;   // ushort[K*64] bf16 hi, XOR-swizzled
constexpr int WS_WLO    = WS_WHI + K_CODE * D_DIM / 2;  // ushort[K*64] bf16 lo, XOR-swizzled
constexpr int WS_CNF    = WS_WLO + K_CODE * D_DIM / 2;  // float[K]: ||c||^2 + 64 (exact f32)

typedef __attribute__((ext_vector_type(16))) float floatx16;
typedef __attribute__((ext_vector_type(8)))  short short8;
typedef __attribute__((ext_vector_type(8)))  __bf16 bf16x8;

// SFINAE hedge: mfma bf16 builtin takes v8bf16 on newer clang, v8i16 on older.
template <typename T, typename = void> struct mfma_takes : std::false_type {};
template <typename T>
struct mfma_takes<T, std::void_t<decltype(__builtin_amdgcn_mfma_f32_32x32x16_bf16(
    std::declval<T>(), std::declval<T>(), std::declval<floatx16>(), 0, 0, 0))>>
    : std::true_type {};

__device__ __forceinline__ floatx16 MFMA(short8 a, short8 b, floatx16 c) {
  if constexpr (mfma_takes<bf16x8>::value) {
    return __builtin_amdgcn_mfma_f32_32x32x16_bf16(
        __builtin_bit_cast(bf16x8, a), __builtin_bit_cast(bf16x8, b), c, 0, 0, 0);
  } else {
    return __builtin_amdgcn_mfma_f32_32x32x16_bf16(a, b, c, 0, 0, 0);
  }
}

__device__ __forceinline__ unsigned short bf16rne(float x) {
  unsigned int u = __float_as_uint(x);
  return (unsigned short)((u + 0x7FFFu + ((u >> 16) & 1u)) >> 16);
}

// async global->LDS 16B DMA (HW writes LDS at wave-uniform dst + lane*16)
__device__ __forceinline__ void gload_lds16(const unsigned short* g, unsigned short* l) {
#if defined(__has_builtin) && __has_builtin(__builtin_amdgcn_global_load_lds)
  typedef __attribute__((address_space(1))) void gvoid;
  typedef __attribute__((address_space(3))) void lvoid;
  __builtin_amdgcn_global_load_lds((gvoid*)g, (lvoid*)l, 16, 0, 0);
#else
  *(uint4*)l = *(const uint4*)g;   // sync fallback (builtin exists on gfx950)
#endif
}

// ---------------------------------------------------------------------------
// Split W into bf16 hi/lo, stored XOR-SWIZZLED (granule g -> g^(k&7), stride
// 64 shorts) so global_load_lds's linear copy lands conflict-managed in LDS.
// Store ||c||^2 + 64 as exact f32. NSUM: one atomic per block into 8
// line-spread slots. Folds counts/embsum zeroing in.
__global__ void vq_prep(const float* __restrict__ w, const float* __restrict__ cs,
                        float* __restrict__ ws) {
  const int tid = threadIdx.x;
  const int gid = blockIdx.x * 256 + tid;   // 0 .. K*D-1
  ws[WS_EMBSUM + gid] = 0.0f;
  if (gid < K_CODE) ws[WS_COUNTS + gid] = 0.0f;

  const int d = tid & 63;                 // dim
  const int kw = tid >> 6;                // 0..3
  const int k = blockIdx.x * 4 + kw;
  const float v = w[(size_t)k * D_DIM + d];
  const unsigned short h = bf16rne(v);
  const float hf = __uint_as_float((unsigned int)h << 16);
  const unsigned short l = bf16rne(v - hf);
  unsigned short* whi = (unsigned short*)(ws + WS_WHI);
  unsigned short* wlo = (unsigned short*)(ws + WS_WLO);
  const int pos = k * D_DIM + (((d >> 3) ^ (k & 7)) * 8) + (d & 7);
  whi[pos] = h;
  wlo[pos] = l;
  float s = v * v;
#pragma unroll
  for (int m = 32; m >= 1; m >>= 1) s += __shfl_xor(s, m);
  __shared__ float csp[4];
  if (d == 0) {
    (ws + WS_CNF)[k] = s + 64.0f;
    csp[kw] = cs[k];
  }
  __syncthreads();
  if (tid == 0) {
    atomicAdd(ws + WS_NSUM + ((blockIdx.x & 7) << 5),
              DECAY * (csp[0] + csp[1] + csp[2] + csp[3]));
  }
}

// ---------------------------------------------------------------------------
// Fused split-bf16 MFMA distance + argmin + segment-sum scatter.
//
// R7: TWO BARRIER DOMAINS + SPLIT CHAINS. R6 (1 block/CU) showed all pipes
// <40% busy with wall 4343 cyc/stage — latency-bound: the single barrier
// domain removed the R4 mechanism where a second, phase-independent block
// fills each block's stall windows. R4 itself was chain-latency-bound
// (12 dependent MFMAs x ~160cy ~= its 2013cy block-stage wall).
// Fix both: (a) block = 256 thr = 4 waves (2 token-pair-groups x 2 code
// halves), 128 tok/block, grid 512 = 2 independent blocks/CU, keeping R6's
// halved per-wave B re-read (64 tok/wave, 24 MFMA + 8 ds_read per stage);
// (b) each acc splits into accA (init cn-splat; G1 + 2 bl-products) and
// accB (first link takes kZero C; G2 + 2 bl-products), summed at the kmin
// update — chain depth 12 -> 6, 4 independent chains/wave.
//
// Body schedule (R4's proven read-ahead): bl(s) ds_reads issue first,
// covered by the 16 bh-consuming MFMAs; bh(s+1) ds_read sits after them
// (register WAR pins it), covered by the 8 bl-MFMAs + kmin + barrier.
//
// Pipeline safety: each fenced region issues exactly {4 DMA, 1 cnf} = 5 vm
// ops; vmcnt(5) at region s retires region s-1's 5 ops (incl. the DMA for
// buf (s+1)&3) before barrier(s) publishes it block-wide. DMA(s+2) issues
// 2 stages ahead. 4 bufs: buf b's ds_reads complete before their consumer
// MFMAs/kmin (data dep), hence before the NEXT barrier; the overwriting
// DMA is 2+ barriers later => no race. Branchless wrap keeps vm-op counts
// uniform (tail DMAs land in dead buffers).
__global__ __launch_bounds__(256, 2) void vq_argmin(
    const float* __restrict__ z, float* __restrict__ ws)
{
  __shared__ __align__(16) unsigned short Wbuf[2][4][2][32 * 64]; // [half][buf][plane]
  __shared__ float mind_s[2][128];
  __shared__ int   tok_s[2][128];

  const int tid  = threadIdx.x;
  const int w    = tid >> 6;    // wave 0..3
  const int lane = tid & 63;
  const int m    = lane & 31;   // A row (token) / B col (code) in tile
  const int h    = lane >> 5;   // k-half selector
  const int tgp  = w & 1;       // token-pair group (64 tokens)
  const int hw   = w >> 1;      // code half (4096 codes)
  const int tb   = blockIdx.x * 128;

  const unsigned short* whi = (const unsigned short*)(ws + WS_WHI);
  const unsigned short* wlo = (const unsigned short*)(ws + WS_WLO);
  const float*          cnf = ws + WS_CNF;

  // ---- A fragments: bf16 hi/lo split of -2*z for 2x32 token rows ----
  short8 ah_a[4], al_a[4], ah_b[4], al_b[4];
  float znorm_a = 0.f, znorm_b = 0.f;
  auto loadA = [&](int sub, short8* AH, short8* AL, float& zn) {
    const float* zrow =
        z + (size_t)(tb + tgp * 64 + sub * 32 + m) * D_DIM + 8 * h;
#pragma unroll
    for (int s4 = 0; s4 < 4; ++s4) {
      const float4 v0 = *(const float4*)(zrow + 16 * s4);
      const float4 v1 = *(const float4*)(zrow + 16 * s4 + 4);
      const float vals[8] = {v0.x, v0.y, v0.z, v0.w, v1.x, v1.y, v1.z, v1.w};
#pragma unroll
      for (int j = 0; j < 8; ++j) {
        const float x = vals[j];
        zn += x * x;
        const float y = -2.0f * x;
        const unsigned short hb = bf16rne(y);
        const float hf = __uint_as_float((unsigned int)hb << 16);
        const unsigned short lb = bf16rne(y - hf);
        AH[s4][j] = (short)hb;
        AL[s4][j] = (short)lb;
      }
    }
    zn += __shfl_xor(zn, 32);   // other k-half of the same token row
  };
  loadA(0, ah_a, al_a, znorm_a);
  loadA(1, ah_b, al_b, znorm_b);

  float kmin0[16], kmin1[16];
#pragma unroll
  for (int r = 0; r < 16; ++r) { kmin0[r] = 3.4e38f; kmin1[r] = 3.4e38f; }

  // ---- DMA staging: stage = 16 KB as 16 x 1KB segments; wave w moves
  // segments 4w..4w+3. seg t: half=t>>3, plane=(t>>2)&1, quarter=t&3.
  auto issueStage = [&](int sIdx, int bufIdx) {
#pragma unroll
    for (int i = 0; i < 4; ++i) {
      const int t = w * 4 + i;
      const int half = t >> 3, plane = (t >> 2) & 1, seg = t & 3;
      const unsigned short* src = (plane ? wlo : whi)
          + ((size_t)half * 4096 + (size_t)sIdx * 32) * D_DIM + seg * 512 + lane * 8;
      unsigned short* dst = &Wbuf[half][bufIdx][plane][seg * 512];  // wave-uniform
      gload_lds16(src, dst);
    }
  };

  // precomputed per-lane B read offsets (shorts) into the pre-swizzled rows
  int xoff[4];
#pragma unroll
  for (int s4 = 0; s4 < 4; ++s4) xoff[s4] = ((2 * s4 + h) ^ (m & 7)) * 8;
  const int mrow = m * 64;
  const int cbase = hw * 4096;

#define LOADBH(BH, BUF) do {                                          \
    const unsigned short* _p = &Wbuf[hw][(BUF)][0][mrow];             \
    BH[0] = *(const short8*)(_p + xoff[0]);                           \
    BH[1] = *(const short8*)(_p + xoff[1]);                           \
    BH[2] = *(const short8*)(_p + xoff[2]);                           \
    BH[3] = *(const short8*)(_p + xoff[3]);                           \
  } while (0)

#define LOADBL(BL, BUF) do {                                          \
    const unsigned short* _p = &Wbuf[hw][(BUF)][1][mrow];             \
    BL[0] = *(const short8*)(_p + xoff[0]);                           \
    BL[1] = *(const short8*)(_p + xoff[1]);                           \
    BL[2] = *(const short8*)(_p + xoff[2]);                           \
    BL[3] = *(const short8*)(_p + xoff[3]);                           \
  } while (0)

  // ---- prologue: 2 stages of DMA, drain once, prime bh <- stage 0 ----
  issueStage(0, 0);
  issueStage(1, 1);
  float cn_cur = cnf[cbase + m];
  asm volatile("s_waitcnt vmcnt(0)" ::: "memory");
  __builtin_amdgcn_s_barrier();
  asm volatile("" ::: "memory");

  short8 bh[4], bl[4];
  LOADBH(bh, 0);
  const floatx16 kZero = {};

  for (int s = 0; s < 128; ++s) {
    // region s: issue exactly {4 DMA, 1 cnf} = 5 vm ops
    issueStage((s + 2) & 127, (s + 2) & 3);
    const float cn_next = cnf[cbase + ((s + 1) & 127) * 32 + m];
    asm volatile("s_waitcnt vmcnt(5)" ::: "memory");
    __builtin_amdgcn_s_barrier();
    asm volatile("" ::: "memory");

    LOADBL(bl, s & 3);                       // covered by the 16 bh-MFMAs

    floatx16 cnv;
#pragma unroll
    for (int r = 0; r < 16; ++r) cnv[r] = cn_cur;

    floatx16 A0, B0, A1, B1;
    __builtin_amdgcn_s_setprio(1);
    // bh-consuming MFMAs first (4 chains interleaved; accB starts from kZero)
    A0 = MFMA(ah_a[0], bh[0], cnv);   A1 = MFMA(ah_b[0], bh[0], cnv);
    B0 = MFMA(al_a[0], bh[0], kZero); B1 = MFMA(al_b[0], bh[0], kZero);
    A0 = MFMA(ah_a[1], bh[1], A0);    A1 = MFMA(ah_b[1], bh[1], A1);
    B0 = MFMA(al_a[1], bh[1], B0);    B1 = MFMA(al_b[1], bh[1], B1);
    A0 = MFMA(ah_a[2], bh[2], A0);    A1 = MFMA(ah_b[2], bh[2], A1);
    B0 = MFMA(al_a[2], bh[2], B0);    B1 = MFMA(al_b[2], bh[2], B1);
    A0 = MFMA(ah_a[3], bh[3], A0);    A1 = MFMA(ah_b[3], bh[3], A1);
    B0 = MFMA(al_a[3], bh[3], B0);    B1 = MFMA(al_b[3], bh[3], B1);
    __builtin_amdgcn_s_setprio(0);

    LOADBH(bh, (s + 1) & 3);                 // WAR pins after all bh reads;
                                             // covered by bl-MFMAs+kmin+barrier
    __builtin_amdgcn_s_setprio(1);
    // bl-products, 2 per chain (chain depth stays 6)
    A0 = MFMA(ah_a[0], bl[0], A0);    A1 = MFMA(ah_b[0], bl[0], A1);
    B0 = MFMA(ah_a[2], bl[2], B0);    B1 = MFMA(ah_b[2], bl[2], B1);
    A0 = MFMA(ah_a[1], bl[1], A0);    A1 = MFMA(ah_b[1], bl[1], A1);
    B0 = MFMA(ah_a[3], bl[3], B0);    B1 = MFMA(ah_b[3], bl[3], B1);
    __builtin_amdgcn_s_setprio(0);

    // packed-key argmin on accA+accB: value > 0; low byte := stage id
#pragma unroll
    for (int r = 0; r < 16; ++r) {
      const float v0 = A0[r] + B0[r];
      const float v1 = A1[r] + B1[r];
      kmin0[r] = fminf(kmin0[r],
          __uint_as_float((__float_as_uint(v0) & 0xFFFFFF00u) | (unsigned)s));
      kmin1[r] = fminf(kmin1[r],
          __uint_as_float((__float_as_uint(v1) & 0xFFFFFF00u) | (unsigned)s));
    }
    cn_cur = cn_next;
  }
#undef LOADBH
#undef LOADBL

  // ---- reduce over the 32 code-cols per row, carrying origin lane ----
#define REDUCE_WRITE(KM, SUB, ZN) do {                                      \
    _Pragma("unroll")                                                       \
    for (int r = 0; r < 16; ++r) {                                          \
      float kv = KM[r];                                                     \
      int mo = m;                                                           \
      _Pragma("unroll")                                                     \
      for (int mm = 1; mm < 32; mm <<= 1) {                                 \
        const float ov = __shfl_xor(kv, mm);                                \
        const int   om = __shfl_xor(mo, mm);                                \
        if (ov < kv || (ov == kv && om < mo)) { kv = ov; mo = om; }         \
      }                                                                     \
      const int mr = (r & 3) + 8 * (r >> 2) + 4 * h;                        \
      if (m == mr) {                                                        \
        const unsigned int kb = __float_as_uint(kv);                        \
        const int trow = tgp * 64 + (SUB) * 32 + mr;                        \
        tok_s[hw][trow] = hw * 4096 + (int)(kb & 0xFFu) * 32 + mo;          \
        mind_s[hw][trow] = __uint_as_float(kb & 0xFFFFFF00u) - 64.0f + (ZN);\
      }                                                                     \
    }                                                                       \
  } while (0)

  REDUCE_WRITE(kmin0, 0, znorm_a);
  REDUCE_WRITE(kmin1, 1, znorm_b);
#undef REDUCE_WRITE
  __syncthreads();

  float* counts = ws + WS_COUNTS;
  float* embsum = ws + WS_EMBSUM;

  // merge code-halves (strict '<' keeps half0 on ties), qe partial + counts
  if (tid < 128) {
    const float d0 = mind_s[0][tid], d1 = mind_s[1][tid];
    const int   i0 = tok_s[0][tid],  i1 = tok_s[1][tid];
    const bool t1 = d1 < d0;
    const float dm = t1 ? d1 : d0;
    const int   im = t1 ? i1 : i0;
    tok_s[0][tid] = im;
    float qe = dm;
#pragma unroll
    for (int mm = 32; mm >= 1; mm >>= 1) qe += __shfl_xor(qe, mm);
    if ((tid & 63) == 0) atomicAdd(ws + WS_QE, qe);
    atomicAdd(&counts[im], 1.0f);
  }
  __syncthreads();

  // segment-sum of z: wave-coalesced atomics (64 consecutive floats/instr)
#pragma unroll 4
  for (int t = 0; t < 32; ++t) {
    const int row = w * 32 + t;
    const int tk = tok_s[0][row];
    const float zv = z[(size_t)(tb + row) * D_DIM + lane];
    atomicAdd(&embsum[(size_t)tk * D_DIM + lane], zv);
  }
}

// ---------------------------------------------------------------------------
// Fused finalize: n = 0.9*sum(cs) + 0.1*N_TOK is precomputed by vq_prep
// (sum(counts) == N_TOK exactly), so ncs/nea/weight all finalize in one pass.
__global__ void vq_finalize(const float* __restrict__ cluster_size,
                            const float* __restrict__ embed_avg,
                            const float* __restrict__ ws, float* __restrict__ out)
{
  const int idx = blockIdx.x * 256 + threadIdx.x;   // over K*D
  const int k = idx >> 6;
  const float ncs = cluster_size[k] * DECAY + OMD * ws[WS_COUNTS + k];
  const float nea = embed_avg[idx] * DECAY + OMD * ws[WS_EMBSUM + idx];
  out[OUT_EA + idx] = nea;
  float n = OMD * (float)N_TOK;
#pragma unroll
  for (int i = 0; i < 8; ++i) n += ws[WS_NSUM + (i << 5)];
  const float sm = (ncs + EPS) / (n + K_CODE * EPS) * n;
  out[OUT_W + idx] = nea / sm;
  if ((idx & 63) == 0) out[OUT_CS + k] = ncs;
  if (idx == 0) out[OUT_QE] = ws[WS_QE] * (1.0f / N_TOK);
}

// ---------------------------------------------------------------------------
extern "C" void kernel_launch(void* const* d_in, const int* in_sizes, int n_in,
                              void* d_out, int out_size, void* d_ws, size_t ws_size,
                              hipStream_t stream) {
  const float* z  = (const float*)d_in[0];
  const float* w  = (const float*)d_in[1];
  const float* cs = (const float*)d_in[2];
  const float* ea = (const float*)d_in[3];
  float* out = (float*)d_out;
  float* ws  = (float*)d_ws;

  // header only (QE + NSUM slots); counts/embsum zeroing folded into vq_prep
  (void)hipMemsetAsync(d_ws, 0, (size_t)WS_COUNTS * sizeof(float), stream);

  vq_prep<<<K_CODE / 4, 256, 0, stream>>>(w, cs, ws);
  vq_argmin<<<N_TOK / 128, 256, 0, stream>>>(z, ws);
  vq_finalize<<<K_CODE * D_DIM / 256, 256, 0, stream>>>(cs, ea, ws, out);
}